// Round 1
// baseline (17637.340 us; speedup 1.0000x reference)
//
#include <hip/hip_runtime.h>
#include <hip/hip_bf16.h>

#define DD 300        // EMB
#define C4 75         // DD/4 float4 chunks per row
#define BN_EPS 1e-5f

// ---------- dtype helpers ----------
__device__ __forceinline__ float cvt_in(float v) { return v; }
__device__ __forceinline__ float cvt_in(__hip_bfloat16 v) { return __bfloat162float(v); }
__device__ __forceinline__ void cvt_out(float* p, float v) { *p = v; }
__device__ __forceinline__ void cvt_out(__hip_bfloat16* p, float v) { *p = __float2bfloat16(v); }

// ---------- h0 = x_emb1[x[:,0]] + x_emb2[x[:,1]] ----------
__global__ __launch_bounds__(256) void embed_kernel(
    const int* __restrict__ x, const float* __restrict__ emb1,
    const float* __restrict__ emb2, float* __restrict__ h, int total4)
{
    int i = blockIdx.x * 256 + threadIdx.x;
    if (i >= total4) return;
    int node = i / C4, chunk = i % C4;
    int a = x[2 * node], b = x[2 * node + 1];
    int c = chunk << 2;
    float4 v1 = *(const float4*)(emb1 + (size_t)a * DD + c);
    float4 v2 = *(const float4*)(emb2 + (size_t)b * DD + c);
    float4 r;
    r.x = v1.x + v2.x; r.y = v1.y + v2.y; r.z = v1.z + v2.z; r.w = v1.w + v2.w;
    *(float4*)(h + (size_t)node * DD + c) = r;
}

// ---------- scatter: agg[dst] += affine(h[src]) + e_emb1[a0] + e_emb2[a1] ----------
// edges [0,E): from edge_index/edge_attr; edges [E,E+n): self loops (i,i,attr=(4,0))
__global__ __launch_bounds__(256) void scatter_kernel(
    const float* __restrict__ h, const int* __restrict__ ei, const int* __restrict__ ea,
    const float* __restrict__ e1, const float* __restrict__ e2,
    const float* __restrict__ scale, const float* __restrict__ shift, int use_affine,
    float* __restrict__ agg, int E, int n)
{
    int gid = blockIdx.x * 256 + threadIdx.x;
    int total = (E + n) * C4;
    if (gid >= total) return;
    int edge = gid / C4;
    int chunk = gid - edge * C4;
    int s, dt, a0, a1;
    if (edge < E) {
        s = ei[edge]; dt = ei[E + edge];
        a0 = ea[2 * edge]; a1 = ea[2 * edge + 1];
    } else {
        int v = edge - E; s = v; dt = v; a0 = 4; a1 = 0;
    }
    int c = chunk << 2;
    float4 hv = *(const float4*)(h + (size_t)s * DD + c);
    if (use_affine) {  // BN affine + ReLU of the previous layer, fused into the read
        hv.x = fmaxf(fmaf(scale[c + 0], hv.x, shift[c + 0]), 0.f);
        hv.y = fmaxf(fmaf(scale[c + 1], hv.y, shift[c + 1]), 0.f);
        hv.z = fmaxf(fmaf(scale[c + 2], hv.z, shift[c + 2]), 0.f);
        hv.w = fmaxf(fmaf(scale[c + 3], hv.w, shift[c + 3]), 0.f);
    }
    float4 ev1 = *(const float4*)(e1 + (size_t)a0 * DD + c);
    float4 ev2 = *(const float4*)(e2 + (size_t)a1 * DD + c);
    float* dst = agg + (size_t)dt * DD + c;
    atomicAdd(dst + 0, hv.x + ev1.x + ev2.x);
    atomicAdd(dst + 1, hv.y + ev1.y + ev2.y);
    atomicAdd(dst + 2, hv.z + ev1.z + ev2.z);
    atomicAdd(dst + 3, hv.w + ev1.w + ev2.w);
}

// ---------- C = act(A @ W^T + bias), A:[M,K], W:[N,K] row-major ----------
// 128x128 tile, BK=8, 256 threads, 8x8 micro-tile
template <typename TIN, typename TOUT, bool RELU>
__global__ __launch_bounds__(256) void gemm_bias(
    const TIN* __restrict__ A, const float* __restrict__ W,
    const float* __restrict__ bias, TOUT* __restrict__ C, int M, int N, int K)
{
    __shared__ float As[8][128];
    __shared__ float Bs[8][128];
    const int tid = threadIdx.x;
    const int bm = blockIdx.y << 7;
    const int bn = blockIdx.x << 7;
    const int tx = tid & 15, ty = tid >> 4;
    const int lr = tid >> 1;          // 0..127
    const int lk = (tid & 1) << 2;    // 0 or 4

    float acc[8][8];
#pragma unroll
    for (int i = 0; i < 8; i++)
#pragma unroll
        for (int j = 0; j < 8; j++) acc[i][j] = 0.f;

    for (int k0 = 0; k0 < K; k0 += 8) {
        {
            int row = bm + lr;
            int wrow = bn + lr;
#pragma unroll
            for (int i = 0; i < 4; i++) {
                int k = k0 + lk + i;
                float va = 0.f, vb = 0.f;
                if (row < M && k < K) va = cvt_in(A[(size_t)row * K + k]);
                if (wrow < N && k < K) vb = W[(size_t)wrow * K + k];
                As[lk + i][lr] = va;
                Bs[lk + i][lr] = vb;
            }
        }
        __syncthreads();
#pragma unroll
        for (int kk = 0; kk < 8; kk++) {
            float4 a0 = *(const float4*)&As[kk][ty << 3];
            float4 a1 = *(const float4*)&As[kk][(ty << 3) + 4];
            float4 b0 = *(const float4*)&Bs[kk][tx << 3];
            float4 b1 = *(const float4*)&Bs[kk][(tx << 3) + 4];
            float a[8] = {a0.x, a0.y, a0.z, a0.w, a1.x, a1.y, a1.z, a1.w};
            float b[8] = {b0.x, b0.y, b0.z, b0.w, b1.x, b1.y, b1.z, b1.w};
#pragma unroll
            for (int i = 0; i < 8; i++)
#pragma unroll
                for (int j = 0; j < 8; j++)
                    acc[i][j] = fmaf(a[i], b[j], acc[i][j]);
        }
        __syncthreads();
    }
#pragma unroll
    for (int i = 0; i < 8; i++) {
        int m = bm + (ty << 3) + i;
        if (m >= M) continue;
#pragma unroll
        for (int j = 0; j < 8; j++) {
            int nn = bn + (tx << 3) + j;
            if (nn >= N) continue;
            float v = acc[i][j] + bias[nn];
            if (RELU) v = fmaxf(v, 0.f);
            cvt_out(&C[(size_t)m * N + nn], v);
        }
    }
}

// ---------- per-column sum / sumsq over rows ----------
// grid*block stride must be a multiple of C4 so each thread owns fixed columns
__global__ __launch_bounds__(256) void stats_kernel(
    const float* __restrict__ h, float* __restrict__ sum, float* __restrict__ sumsq,
    int total4)
{
    int idx = blockIdx.x * 256 + threadIdx.x;
    int stride = gridDim.x * 256;
    int c = (idx % C4) << 2;
    float s0 = 0, s1 = 0, s2 = 0, s3 = 0, q0 = 0, q1 = 0, q2 = 0, q3 = 0;
    const float4* h4 = (const float4*)h;
    for (int i = idx; i < total4; i += stride) {
        float4 v = h4[i];
        s0 += v.x; q0 += v.x * v.x;
        s1 += v.y; q1 += v.y * v.y;
        s2 += v.z; q2 += v.z * v.z;
        s3 += v.w; q3 += v.w * v.w;
    }
    atomicAdd(&sum[c + 0], s0); atomicAdd(&sumsq[c + 0], q0);
    atomicAdd(&sum[c + 1], s1); atomicAdd(&sumsq[c + 1], q1);
    atomicAdd(&sum[c + 2], s2); atomicAdd(&sumsq[c + 2], q2);
    atomicAdd(&sum[c + 3], s3); atomicAdd(&sumsq[c + 3], q3);
}

// ---------- fold BN stats into per-column scale/shift ----------
__global__ void finalize_kernel(
    const float* __restrict__ sum, const float* __restrict__ sumsq,
    const float* __restrict__ gamma, const float* __restrict__ beta,
    float* __restrict__ scale, float* __restrict__ shift, float inv_n)
{
    int c = threadIdx.x;
    if (c < DD) {
        float mu = sum[c] * inv_n;
        float var = sumsq[c] * inv_n - mu * mu;
        float inv = rsqrtf(var + BN_EPS);
        float sc = gamma[c] * inv;
        scale[c] = sc;
        shift[c] = fmaf(-mu, sc, beta[c]);
    }
}

// ---------- final: out = scale*h + shift (no ReLU on last layer) ----------
__global__ __launch_bounds__(256) void apply_kernel(
    const float* __restrict__ h, const float* __restrict__ scale,
    const float* __restrict__ shift, float* __restrict__ out, int total4)
{
    int i = blockIdx.x * 256 + threadIdx.x;
    if (i >= total4) return;
    int c = (i % C4) << 2;
    float4 v = ((const float4*)h)[i];
    float4 r;
    r.x = fmaf(scale[c + 0], v.x, shift[c + 0]);
    r.y = fmaf(scale[c + 1], v.y, shift[c + 1]);
    r.z = fmaf(scale[c + 2], v.z, shift[c + 2]);
    r.w = fmaf(scale[c + 3], v.w, shift[c + 3]);
    ((float4*)out)[i] = r;
}

extern "C" void kernel_launch(void* const* d_in, const int* in_sizes, int n_in,
                              void* d_out, int out_size, void* d_ws, size_t ws_size,
                              hipStream_t stream)
{
    const int*   x      = (const int*)d_in[0];
    const int*   ei     = (const int*)d_in[1];
    const int*   ea     = (const int*)d_in[2];
    const float* x_emb1 = (const float*)d_in[3];
    const float* x_emb2 = (const float*)d_in[4];
    const float* e_emb1 = (const float*)d_in[5];
    const float* e_emb2 = (const float*)d_in[6];
    const float* w1     = (const float*)d_in[7];
    const float* b1     = (const float*)d_in[8];
    const float* w2     = (const float*)d_in[9];
    const float* b2     = (const float*)d_in[10];
    const float* gamma  = (const float*)d_in[11];
    const float* beta   = (const float*)d_in[12];

    const int n = in_sizes[0] / 2;   // 100000
    const int E = in_sizes[1] / 2;   // 250000

    // workspace: h (n*300 f32) | hid (n*600 bf16) | stats
    float* h = (float*)d_ws;
    __hip_bfloat16* hid = (__hip_bfloat16*)(h + (size_t)n * DD);
    float* stats = (float*)((char*)hid + (size_t)n * 600 * sizeof(__hip_bfloat16));
    float* sum   = stats;
    float* sumsq = stats + 320;
    float* scale = stats + 640;
    float* shift = stats + 960;
    float* agg = (float*)d_out;   // scratch; overwritten by apply_kernel at the end

    const int total4 = n * C4;
    const int et4 = (E + n) * C4;

    embed_kernel<<<(total4 + 255) / 256, 256, 0, stream>>>(x, x_emb1, x_emb2, h, total4);

    for (int l = 0; l < 5; l++) {
        hipMemsetAsync(agg, 0, (size_t)n * DD * sizeof(float), stream);
        hipMemsetAsync(sum, 0, 640 * sizeof(float), stream);  // zero sum+sumsq only
        scatter_kernel<<<(et4 + 255) / 256, 256, 0, stream>>>(
            h, ei, ea, e_emb1 + (size_t)l * 6 * DD, e_emb2 + (size_t)l * 3 * DD,
            scale, shift, l > 0 ? 1 : 0, agg, E, n);
        dim3 g1((600 + 127) / 128, (n + 127) / 128);
        gemm_bias<float, __hip_bfloat16, true><<<g1, 256, 0, stream>>>(
            agg, w1 + (size_t)l * 600 * DD, b1 + (size_t)l * 600, hid, n, 600, DD);
        dim3 g2((DD + 127) / 128, (n + 127) / 128);
        gemm_bias<__hip_bfloat16, float, false><<<g2, 256, 0, stream>>>(
            hid, w2 + (size_t)l * DD * 600, b2 + (size_t)l * DD, h, n, DD, 600);
        stats_kernel<<<600, 256, 0, stream>>>(h, sum, sumsq, total4);
        finalize_kernel<<<1, 320, 0, stream>>>(sum, sumsq, gamma + (size_t)l * DD,
                                               beta + (size_t)l * DD, scale, shift,
                                               1.0f / (float)n);
    }
    apply_kernel<<<(total4 + 255) / 256, 256, 0, stream>>>(h, scale, shift,
                                                           (float*)d_out, total4);
}

// Round 2
// 5580.054 us; speedup vs baseline: 3.1608x; 3.1608x over previous
//
#include <hip/hip_runtime.h>
#include <hip/hip_bf16.h>

#define DD 300        // EMB
#define C4 75         // DD/4 float4 chunks per row
#define BN_EPS 1e-5f

typedef short s16x8 __attribute__((ext_vector_type(8)));   // 8 bf16 in 4 VGPRs
typedef float f32x4 __attribute__((ext_vector_type(4)));

union Pack4 { __hip_bfloat16 b[4]; uint2 u; };

__device__ __forceinline__ void split_hl(float v, __hip_bfloat16& hi, __hip_bfloat16& lo) {
    hi = __float2bfloat16(v);
    lo = __float2bfloat16(v - __bfloat162float(hi));
}

// ---------- h0 = x_emb1[x[:,0]] + x_emb2[x[:,1]] ----------
__global__ __launch_bounds__(256) void embed_kernel(
    const int* __restrict__ x, const float* __restrict__ emb1,
    const float* __restrict__ emb2, float* __restrict__ h, int total4)
{
    int i = blockIdx.x * 256 + threadIdx.x;
    if (i >= total4) return;
    int node = i / C4, chunk = i - node * C4;
    int a = x[2 * node], b = x[2 * node + 1];
    int c = chunk << 2;
    float4 v1 = *(const float4*)(emb1 + (size_t)a * DD + c);
    float4 v2 = *(const float4*)(emb2 + (size_t)b * DD + c);
    float4 r;
    r.x = v1.x + v2.x; r.y = v1.y + v2.y; r.z = v1.z + v2.z; r.w = v1.w + v2.w;
    *(float4*)(h + (size_t)node * DD + c) = r;
}

// ---------- combined edge-embedding table: ec[l][a0*3+a1][c] ----------
__global__ __launch_bounds__(256) void build_ec_kernel(
    const float* __restrict__ e1, const float* __restrict__ e2, float* __restrict__ ec)
{
    int gid = blockIdx.x * 256 + threadIdx.x;
    if (gid >= 5 * 18 * DD) return;
    int l = gid / (18 * DD);
    int rem = gid - l * 18 * DD;
    int combo = rem / DD;
    int c = rem - combo * DD;
    int a0 = combo / 3, a1 = combo - a0 * 3;
    ec[gid] = e1[(size_t)l * 6 * DD + a0 * DD + c] + e2[(size_t)l * 3 * DD + a1 * DD + c];
}

// ---------- per-dst linked list: head[dst] -> chain of edges ----------
__global__ __launch_bounds__(256) void build_links_kernel(
    const int* __restrict__ ei, const int* __restrict__ ea,
    int* __restrict__ head, int2* __restrict__ links, int E)
{
    int e = blockIdx.x * 256 + threadIdx.x;
    if (e >= E) return;
    int src = ei[e];
    int dst = ei[E + e];
    int combo = ea[2 * e] * 3 + ea[2 * e + 1];
    int old = atomicExch(&head[dst], e);
    links[e] = make_int2(old, src | (combo << 18));
}

// ---------- gather: agg[i] = sum over in-edges of affine(h[src]) + ec[combo], + self ----------
// writes bf16 hi/lo split, K padded to 320 (chunks 75..79 zeroed)
__global__ __launch_bounds__(256) void gather_kernel(
    const float* __restrict__ h, const int* __restrict__ head,
    const int2* __restrict__ links, const float* __restrict__ ec,
    const float* __restrict__ scale, const float* __restrict__ shift, int use_affine,
    __hip_bfloat16* __restrict__ aggH, __hip_bfloat16* __restrict__ aggL, int n)
{
    int gid = blockIdx.x * 256 + threadIdx.x;
    int node = gid / 80, ch = gid - node * 80;
    if (node >= n) return;
    size_t obase = (size_t)node * 320 + (ch << 2);
    if (ch >= 75) {  // zero the k-pad columns 300..319
        uint2 z = make_uint2(0u, 0u);
        *(uint2*)(aggH + obase) = z;
        *(uint2*)(aggL + obase) = z;
        return;
    }
    int c = ch << 2;
    float4 sc, sh;
    if (use_affine) {
        sc = *(const float4*)(scale + c);
        sh = *(const float4*)(shift + c);
    }
    // self-loop: combo = 4*3+0 = 12
    float4 acc = *(const float4*)(h + (size_t)node * DD + c);
    if (use_affine) {
        acc.x = fmaxf(fmaf(sc.x, acc.x, sh.x), 0.f);
        acc.y = fmaxf(fmaf(sc.y, acc.y, sh.y), 0.f);
        acc.z = fmaxf(fmaf(sc.z, acc.z, sh.z), 0.f);
        acc.w = fmaxf(fmaf(sc.w, acc.w, sh.w), 0.f);
    }
    float4 es = *(const float4*)(ec + 12 * DD + c);
    acc.x += es.x; acc.y += es.y; acc.z += es.z; acc.w += es.w;

    for (int e = head[node]; e >= 0; ) {
        int2 lk = links[e];
        e = lk.x;
        int src = lk.y & 0x3FFFF;
        int combo = lk.y >> 18;
        float4 hv = *(const float4*)(h + (size_t)src * DD + c);
        if (use_affine) {
            hv.x = fmaxf(fmaf(sc.x, hv.x, sh.x), 0.f);
            hv.y = fmaxf(fmaf(sc.y, hv.y, sh.y), 0.f);
            hv.z = fmaxf(fmaf(sc.z, hv.z, sh.z), 0.f);
            hv.w = fmaxf(fmaf(sc.w, hv.w, sh.w), 0.f);
        }
        float4 ev = *(const float4*)(ec + combo * DD + c);
        acc.x += hv.x + ev.x;
        acc.y += hv.y + ev.y;
        acc.z += hv.z + ev.z;
        acc.w += hv.w + ev.w;
    }
    Pack4 ph, pl;
    split_hl(acc.x, ph.b[0], pl.b[0]);
    split_hl(acc.y, ph.b[1], pl.b[1]);
    split_hl(acc.z, ph.b[2], pl.b[2]);
    split_hl(acc.w, ph.b[3], pl.b[3]);
    *(uint2*)(aggH + obase) = ph.u;
    *(uint2*)(aggL + obase) = pl.u;
}

// ---------- convert fp32 weights (out,in) -> padded bf16 hi/lo ----------
__global__ __launch_bounds__(256) void convert_w_kernel(
    const float* __restrict__ w, __hip_bfloat16* __restrict__ wh,
    __hip_bfloat16* __restrict__ wl, int rows, int cols, int rowsP, int colsP)
{
    int gid = blockIdx.x * 256 + threadIdx.x;
    int total = 5 * rowsP * colsP;
    if (gid >= total) return;
    int l = gid / (rowsP * colsP);
    int rem = gid - l * rowsP * colsP;
    int r = rem / colsP;
    int k = rem - r * colsP;
    float v = (r < rows && k < cols) ? w[((size_t)l * rows + r) * cols + k] : 0.f;
    __hip_bfloat16 hi, lo;
    split_hl(v, hi, lo);
    wh[gid] = hi;
    wl[gid] = lo;
}

// ---------- MFMA GEMM: C = act(A @ W^T + bias) ----------
// A: [M, Kp] bf16 (hi + optional lo), W: [NP, Kp] bf16 hi/lo (rows = output cols)
// block = 256 thr = 4 waves (2x2), block tile 64m x 128n, wave tile 32m x 64n
// terms: Ah*Wh + (SPLIT_A ? Al*Wh) + Ah*Wl
template <bool SPLIT_A, bool OUT_BF16>
__global__ __launch_bounds__(256, 3) void mfma_gemm_kernel(
    const __hip_bfloat16* __restrict__ Ah, const __hip_bfloat16* __restrict__ Al,
    const __hip_bfloat16* __restrict__ Wh, const __hip_bfloat16* __restrict__ Wl,
    const float* __restrict__ bias,
    __hip_bfloat16* __restrict__ outB, float* __restrict__ outF,
    int M, int N, int Kp, int outStride)
{
    const int tid = threadIdx.x;
    const int lane = tid & 63, wave = tid >> 6;
    const int wy = wave & 1, wx = wave >> 1;       // 2x2 wave grid
    const int quad = lane >> 4, l16 = lane & 15;
    const int bm = blockIdx.y << 6;                 // 64-row block tile
    const int bn = blockIdx.x << 7;                 // 128-col block tile
    const int kOff = quad << 3;

    f32x4 acc[2][4] = {};

    const int aRow0 = bm + wy * 32 + l16;
    const int wRow0 = bn + wx * 64 + l16;

    for (int k0 = 0; k0 < Kp; k0 += 32) {
        s16x8 ah[2], al[2], wh[4], wl[4];
#pragma unroll
        for (int i = 0; i < 2; i++) {
            size_t off = (size_t)(aRow0 + i * 16) * Kp + k0 + kOff;
            ah[i] = *(const s16x8*)(Ah + off);
            if constexpr (SPLIT_A) al[i] = *(const s16x8*)(Al + off);
        }
#pragma unroll
        for (int j = 0; j < 4; j++) {
            size_t off = (size_t)(wRow0 + j * 16) * Kp + k0 + kOff;
            wh[j] = *(const s16x8*)(Wh + off);
            wl[j] = *(const s16x8*)(Wl + off);
        }
#pragma unroll
        for (int i = 0; i < 2; i++)
#pragma unroll
            for (int j = 0; j < 4; j++) {
                acc[i][j] = __builtin_amdgcn_mfma_f32_16x16x32_bf16(ah[i], wh[j], acc[i][j], 0, 0, 0);
                if constexpr (SPLIT_A)
                    acc[i][j] = __builtin_amdgcn_mfma_f32_16x16x32_bf16(al[i], wh[j], acc[i][j], 0, 0, 0);
                acc[i][j] = __builtin_amdgcn_mfma_f32_16x16x32_bf16(ah[i], wl[j], acc[i][j], 0, 0, 0);
            }
    }

    // epilogue: C/D layout col=lane&15, row=quad*4+reg  [m89-verified]
#pragma unroll
    for (int i = 0; i < 2; i++) {
        int rowBase = bm + wy * 32 + i * 16 + (quad << 2);
#pragma unroll
        for (int j = 0; j < 4; j++) {
            int col = bn + wx * 64 + j * 16 + l16;
            float bv = (col < N) ? bias[col] : 0.f;
#pragma unroll
            for (int r = 0; r < 4; r++) {
                int row = rowBase + r;
                if (row >= M) continue;
                float v = acc[i][j][r] + bv;
                if constexpr (OUT_BF16) {
                    if (col < outStride) {   // outStride = padded K of next GEMM (608)
                        float o = (col < N) ? fmaxf(v, 0.f) : 0.f;  // zero the k-pad
                        outB[(size_t)row * outStride + col] = __float2bfloat16(o);
                    }
                } else {
                    if (col < N) outF[(size_t)row * outStride + col] = v;
                }
            }
        }
    }
}

// ---------- per-column sum / sumsq; grid*block stride multiple of C4 ----------
__global__ __launch_bounds__(256) void stats_kernel(
    const float* __restrict__ h, float* __restrict__ sum, float* __restrict__ sumsq,
    int total4)
{
    int idx = blockIdx.x * 256 + threadIdx.x;
    int stride = gridDim.x * 256;
    int c = (idx % C4) << 2;
    float s0 = 0, s1 = 0, s2 = 0, s3 = 0, q0 = 0, q1 = 0, q2 = 0, q3 = 0;
    const float4* h4 = (const float4*)h;
    for (int i = idx; i < total4; i += stride) {
        float4 v = h4[i];
        s0 += v.x; q0 += v.x * v.x;
        s1 += v.y; q1 += v.y * v.y;
        s2 += v.z; q2 += v.z * v.z;
        s3 += v.w; q3 += v.w * v.w;
    }
    atomicAdd(&sum[c + 0], s0); atomicAdd(&sumsq[c + 0], q0);
    atomicAdd(&sum[c + 1], s1); atomicAdd(&sumsq[c + 1], q1);
    atomicAdd(&sum[c + 2], s2); atomicAdd(&sumsq[c + 2], q2);
    atomicAdd(&sum[c + 3], s3); atomicAdd(&sumsq[c + 3], q3);
}

__global__ void finalize_kernel(
    const float* __restrict__ sum, const float* __restrict__ sumsq,
    const float* __restrict__ gamma, const float* __restrict__ beta,
    float* __restrict__ scale, float* __restrict__ shift, float inv_n)
{
    int c = threadIdx.x;
    if (c < DD) {
        float mu = sum[c] * inv_n;
        float var = sumsq[c] * inv_n - mu * mu;
        float inv = rsqrtf(var + BN_EPS);
        float sc = gamma[c] * inv;
        scale[c] = sc;
        shift[c] = fmaf(-mu, sc, beta[c]);
    }
}

// ---------- final: out = scale*h + shift (in-place on d_out) ----------
__global__ __launch_bounds__(256) void apply_kernel(
    const float* __restrict__ h, const float* __restrict__ scale,
    const float* __restrict__ shift, float* __restrict__ out, int total4)
{
    int i = blockIdx.x * 256 + threadIdx.x;
    if (i >= total4) return;
    int c = (i % C4) << 2;
    float4 v = ((const float4*)h)[i];
    float4 r;
    r.x = fmaf(scale[c + 0], v.x, shift[c + 0]);
    r.y = fmaf(scale[c + 1], v.y, shift[c + 1]);
    r.z = fmaf(scale[c + 2], v.z, shift[c + 2]);
    r.w = fmaf(scale[c + 3], v.w, shift[c + 3]);
    ((float4*)out)[i] = r;
}

extern "C" void kernel_launch(void* const* d_in, const int* in_sizes, int n_in,
                              void* d_out, int out_size, void* d_ws, size_t ws_size,
                              hipStream_t stream)
{
    const int*   x      = (const int*)d_in[0];
    const int*   ei     = (const int*)d_in[1];
    const int*   ea     = (const int*)d_in[2];
    const float* x_emb1 = (const float*)d_in[3];
    const float* x_emb2 = (const float*)d_in[4];
    const float* e_emb1 = (const float*)d_in[5];
    const float* e_emb2 = (const float*)d_in[6];
    const float* w1     = (const float*)d_in[7];
    const float* b1     = (const float*)d_in[8];
    const float* w2     = (const float*)d_in[9];
    const float* b2     = (const float*)d_in[10];
    const float* gamma  = (const float*)d_in[11];
    const float* beta   = (const float*)d_in[12];

    const int n = in_sizes[0] / 2;     // 100000
    const int E = in_sizes[1] / 2;     // 250000
    const int Mp = ((n + 63) / 64) * 64;   // 100032
    const int Kp1 = 320, Kp2 = 608;        // padded K for GEMM1/GEMM2
    const int NP1 = 640, NP2 = 384;        // padded W rows (5 and 3 n-tiles of 128)

    // ---- workspace layout ----
    char* p = (char*)d_ws;
    auto alloc = [&](size_t bytes) -> void* {
        void* r = (void*)p;
        p += (bytes + 255) & ~(size_t)255;
        return r;
    };
    __hip_bfloat16* aggH = (__hip_bfloat16*)alloc((size_t)Mp * Kp1 * 2);
    __hip_bfloat16* aggL = (__hip_bfloat16*)alloc((size_t)Mp * Kp1 * 2);
    __hip_bfloat16* hid  = (__hip_bfloat16*)alloc((size_t)Mp * Kp2 * 2);
    __hip_bfloat16* w1h  = (__hip_bfloat16*)alloc((size_t)5 * NP1 * Kp1 * 2);
    __hip_bfloat16* w1l  = (__hip_bfloat16*)alloc((size_t)5 * NP1 * Kp1 * 2);
    __hip_bfloat16* w2h  = (__hip_bfloat16*)alloc((size_t)5 * NP2 * Kp2 * 2);
    __hip_bfloat16* w2l  = (__hip_bfloat16*)alloc((size_t)5 * NP2 * Kp2 * 2);
    float* ec    = (float*)alloc((size_t)5 * 18 * DD * 4);
    int*   head  = (int*)alloc((size_t)n * 4);
    int2*  links = (int2*)alloc((size_t)E * 8);
    float* sum   = (float*)alloc(320 * 4);
    float* sumsq = (float*)alloc(320 * 4);
    float* scale = (float*)alloc(320 * 4);
    float* shift = (float*)alloc(320 * 4);

    float* h = (float*)d_out;            // h lives in d_out; final apply is in-place
    const int total4 = n * C4;

    // ---- one-time (per call) prep ----
    {
        int t1 = 5 * NP1 * Kp1;
        convert_w_kernel<<<(t1 + 255) / 256, 256, 0, stream>>>(w1, w1h, w1l, 600, 300, NP1, Kp1);
        int t2 = 5 * NP2 * Kp2;
        convert_w_kernel<<<(t2 + 255) / 256, 256, 0, stream>>>(w2, w2h, w2l, 300, 600, NP2, Kp2);
        int t3 = 5 * 18 * DD;
        build_ec_kernel<<<(t3 + 255) / 256, 256, 0, stream>>>(e_emb1, e_emb2, ec);
        hipMemsetAsync(head, 0xFF, (size_t)n * 4, stream);   // head = -1
        build_links_kernel<<<(E + 255) / 256, 256, 0, stream>>>(ei, ea, head, links, E);
        embed_kernel<<<(total4 + 255) / 256, 256, 0, stream>>>(x, x_emb1, x_emb2, h, total4);
    }

    const int gatherTotal = n * 80;
    dim3 g1(NP1 / 128, Mp / 64);   // (5, 1563)
    dim3 g2(NP2 / 128, Mp / 64);   // (3, 1563)

    for (int l = 0; l < 5; l++) {
        hipMemsetAsync(sum, 0, 2 * 320 * sizeof(float), stream);  // sum+sumsq contiguous
        gather_kernel<<<(gatherTotal + 255) / 256, 256, 0, stream>>>(
            h, head, links, ec + (size_t)l * 18 * DD, scale, shift, l > 0 ? 1 : 0,
            aggH, aggL, n);
        mfma_gemm_kernel<true, true><<<g1, 256, 0, stream>>>(
            aggH, aggL,
            w1h + (size_t)l * NP1 * Kp1, w1l + (size_t)l * NP1 * Kp1,
            b1 + (size_t)l * 600, hid, nullptr, n, 600, Kp1, Kp2);
        mfma_gemm_kernel<false, false><<<g2, 256, 0, stream>>>(
            hid, nullptr,
            w2h + (size_t)l * NP2 * Kp2, w2l + (size_t)l * NP2 * Kp2,
            b2 + (size_t)l * 300, nullptr, h, n, 300, Kp2, 300);
        stats_kernel<<<600, 256, 0, stream>>>(h, sum, sumsq, total4);
        finalize_kernel<<<1, 320, 0, stream>>>(sum, sumsq, gamma + (size_t)l * DD,
                                               beta + (size_t)l * DD, scale, shift,
                                               1.0f / (float)n);
    }
    apply_kernel<<<(total4 + 255) / 256, 256, 0, stream>>>(h, scale, shift, h, total4);
}

// Round 3
// 4089.005 us; speedup vs baseline: 4.3134x; 1.3646x over previous
//
#include <hip/hip_runtime.h>
#include <hip/hip_bf16.h>

#define DD 300        // EMB
#define C4 75         // DD/4 float4 chunks per row
#define BN_EPS 1e-5f

typedef short s16x8 __attribute__((ext_vector_type(8)));   // 8 bf16 in 4 VGPRs
typedef float f32x4 __attribute__((ext_vector_type(4)));

union Pack4 { __hip_bfloat16 b[4]; uint2 u; };

__device__ __forceinline__ void split_hl(float v, __hip_bfloat16& hi, __hip_bfloat16& lo) {
    hi = __float2bfloat16(v);
    lo = __float2bfloat16(v - __bfloat162float(hi));
}

// async global->LDS, 16 B per lane, dest = wave-uniform base + lane*16
__device__ __forceinline__ void gld_lds16(const void* g, void* lds) {
    __builtin_amdgcn_global_load_lds(
        (const __attribute__((address_space(1))) void*)g,
        (__attribute__((address_space(3))) void*)lds, 16, 0, 0);
}

// ---------- h0 = x_emb1[x[:,0]] + x_emb2[x[:,1]] ----------
__global__ __launch_bounds__(256) void embed_kernel(
    const int* __restrict__ x, const float* __restrict__ emb1,
    const float* __restrict__ emb2, float* __restrict__ h, int total4)
{
    int i = blockIdx.x * 256 + threadIdx.x;
    if (i >= total4) return;
    int node = i / C4, chunk = i - node * C4;
    int a = x[2 * node], b = x[2 * node + 1];
    int c = chunk << 2;
    float4 v1 = *(const float4*)(emb1 + (size_t)a * DD + c);
    float4 v2 = *(const float4*)(emb2 + (size_t)b * DD + c);
    float4 r;
    r.x = v1.x + v2.x; r.y = v1.y + v2.y; r.z = v1.z + v2.z; r.w = v1.w + v2.w;
    *(float4*)(h + (size_t)node * DD + c) = r;
}

// ---------- combined edge-embedding table: ec[l][a0*3+a1][c] ----------
__global__ __launch_bounds__(256) void build_ec_kernel(
    const float* __restrict__ e1, const float* __restrict__ e2, float* __restrict__ ec)
{
    int gid = blockIdx.x * 256 + threadIdx.x;
    if (gid >= 5 * 18 * DD) return;
    int l = gid / (18 * DD);
    int rem = gid - l * 18 * DD;
    int combo = rem / DD;
    int c = rem - combo * DD;
    int a0 = combo / 3, a1 = combo - a0 * 3;
    ec[gid] = e1[(size_t)l * 6 * DD + a0 * DD + c] + e2[(size_t)l * 3 * DD + a1 * DD + c];
}

// ---------- per-dst linked list: head[dst] -> chain of edges ----------
__global__ __launch_bounds__(256) void build_links_kernel(
    const int* __restrict__ ei, const int* __restrict__ ea,
    int* __restrict__ head, int2* __restrict__ links, int E)
{
    int e = blockIdx.x * 256 + threadIdx.x;
    if (e >= E) return;
    int src = ei[e];
    int dst = ei[E + e];
    int combo = ea[2 * e] * 3 + ea[2 * e + 1];
    int old = atomicExch(&head[dst], e);
    links[e] = make_int2(old, src | (combo << 18));
}

// ---------- gather: agg[i] = sum over in-edges of affine(h[src]) + ec[combo], + self ----------
__global__ __launch_bounds__(256) void gather_kernel(
    const float* __restrict__ h, const int* __restrict__ head,
    const int2* __restrict__ links, const float* __restrict__ ec,
    const float* __restrict__ scale, const float* __restrict__ shift, int use_affine,
    __hip_bfloat16* __restrict__ aggH, __hip_bfloat16* __restrict__ aggL, int n)
{
    int gid = blockIdx.x * 256 + threadIdx.x;
    int node = gid / 80, ch = gid - node * 80;
    if (node >= n) return;
    size_t obase = (size_t)node * 320 + (ch << 2);
    if (ch >= 75) {  // zero the k-pad columns 300..319
        uint2 z = make_uint2(0u, 0u);
        *(uint2*)(aggH + obase) = z;
        *(uint2*)(aggL + obase) = z;
        return;
    }
    int c = ch << 2;
    float4 sc, sh;
    if (use_affine) {
        sc = *(const float4*)(scale + c);
        sh = *(const float4*)(shift + c);
    }
    float4 acc = *(const float4*)(h + (size_t)node * DD + c);  // self-loop, combo 12
    if (use_affine) {
        acc.x = fmaxf(fmaf(sc.x, acc.x, sh.x), 0.f);
        acc.y = fmaxf(fmaf(sc.y, acc.y, sh.y), 0.f);
        acc.z = fmaxf(fmaf(sc.z, acc.z, sh.z), 0.f);
        acc.w = fmaxf(fmaf(sc.w, acc.w, sh.w), 0.f);
    }
    float4 es = *(const float4*)(ec + 12 * DD + c);
    acc.x += es.x; acc.y += es.y; acc.z += es.z; acc.w += es.w;

    for (int e = head[node]; e >= 0; ) {
        int2 lk = links[e];
        e = lk.x;
        int src = lk.y & 0x3FFFF;
        int combo = lk.y >> 18;
        float4 hv = *(const float4*)(h + (size_t)src * DD + c);
        if (use_affine) {
            hv.x = fmaxf(fmaf(sc.x, hv.x, sh.x), 0.f);
            hv.y = fmaxf(fmaf(sc.y, hv.y, sh.y), 0.f);
            hv.z = fmaxf(fmaf(sc.z, hv.z, sh.z), 0.f);
            hv.w = fmaxf(fmaf(sc.w, hv.w, sh.w), 0.f);
        }
        float4 ev = *(const float4*)(ec + combo * DD + c);
        acc.x += hv.x + ev.x;
        acc.y += hv.y + ev.y;
        acc.z += hv.z + ev.z;
        acc.w += hv.w + ev.w;
    }
    Pack4 ph, pl;
    split_hl(acc.x, ph.b[0], pl.b[0]);
    split_hl(acc.y, ph.b[1], pl.b[1]);
    split_hl(acc.z, ph.b[2], pl.b[2]);
    split_hl(acc.w, ph.b[3], pl.b[3]);
    *(uint2*)(aggH + obase) = ph.u;
    *(uint2*)(aggL + obase) = pl.u;
}

// ---------- convert fp32 weights (out,in) -> padded bf16 hi/lo ----------
__global__ __launch_bounds__(256) void convert_w_kernel(
    const float* __restrict__ w, __hip_bfloat16* __restrict__ wh,
    __hip_bfloat16* __restrict__ wl, int rows, int cols, int rowsP, int colsP)
{
    int gid = blockIdx.x * 256 + threadIdx.x;
    int total = 5 * rowsP * colsP;
    if (gid >= total) return;
    int l = gid / (rowsP * colsP);
    int rem = gid - l * rowsP * colsP;
    int r = rem / colsP;
    int k = rem - r * colsP;
    float v = (r < rows && k < cols) ? w[((size_t)l * rows + r) * cols + k] : 0.f;
    __hip_bfloat16 hi, lo;
    split_hl(v, hi, lo);
    wh[gid] = hi;
    wl[gid] = lo;
}

// ---------- LDS-staged MFMA GEMM over K-concatenated segments ----------
// C = act( sum_s A_s @ W_s^T + bias ),  A_s:[Mp,Kseg] bf16, W_s:[NP,Kseg] bf16
// block 256 thr = 4 waves (2x2), block tile 128m x 128n, wave tile 64x64
// LDS: sA/sB [128 rows][8 chunks of 16B], chunk slot XOR-swizzled by row%8
template <int NSEG, bool OUT_BF16>
__global__ __launch_bounds__(256) void mfma_gemm_lds(
    const __hip_bfloat16* __restrict__ A0, const __hip_bfloat16* __restrict__ A1,
    const __hip_bfloat16* __restrict__ A2,
    const __hip_bfloat16* __restrict__ W0, const __hip_bfloat16* __restrict__ W1s,
    const __hip_bfloat16* __restrict__ W2s,
    const float* __restrict__ bias,
    __hip_bfloat16* __restrict__ outB, float* __restrict__ outF,
    int M, int Kseg, int outStride, int outN)
{
    __shared__ unsigned short sA[128 * 64];
    __shared__ unsigned short sB[128 * 64];

    const int tid = threadIdx.x;
    const int lane = tid & 63, wv = tid >> 6;
    const int wy = wv & 1, wx = wv >> 1;            // 2x2 wave grid
    const int quad = lane >> 4, l16 = lane & 15;
    const int bm = blockIdx.y << 7;
    const int bn = blockIdx.x << 7;

    // staging assignment: call j stages rows wv*32+j*8 .. +7; 8 lanes/row
    const int r8 = lane >> 3;                        // 0..7 row within call
    const int chv = (lane & 7) ^ r8;                 // swizzled chunk to fetch

    const __hip_bfloat16* As[3] = {A0, A1, A2};
    const __hip_bfloat16* Ws[3] = {W0, W1s, W2s};

    f32x4 acc[4][4] = {};

    for (int s = 0; s < NSEG; ++s) {
        const __hip_bfloat16* Ag = As[s];
        const __hip_bfloat16* Wg = Ws[s];
        for (int k0 = 0; k0 < Kseg; k0 += 64) {
            __syncthreads();   // previous iter's ds_reads done before overwrite
#pragma unroll
            for (int j = 0; j < 4; ++j) {
                int rloc = wv * 32 + j * 8 + r8;
                int ldsBase = (wv * 32 + j * 8) * 64;
                gld_lds16(Ag + (size_t)(bm + rloc) * Kseg + k0 + chv * 8, &sA[ldsBase]);
                gld_lds16(Wg + (size_t)(bn + rloc) * Kseg + k0 + chv * 8, &sB[ldsBase]);
            }
            __syncthreads();   // implies s_waitcnt vmcnt(0) drain of global_load_lds
#pragma unroll
            for (int kk = 0; kk < 2; ++kk) {
                s16x8 a[4], b[4];
#pragma unroll
                for (int i = 0; i < 4; ++i) {
                    int rA = wy * 64 + i * 16 + l16;
                    int slotA = (kk * 4 + quad) ^ (rA & 7);
                    a[i] = *(const s16x8*)&sA[rA * 64 + slotA * 8];
                    int rB = wx * 64 + i * 16 + l16;
                    int slotB = (kk * 4 + quad) ^ (rB & 7);
                    b[i] = *(const s16x8*)&sB[rB * 64 + slotB * 8];
                }
#pragma unroll
                for (int i = 0; i < 4; ++i)
#pragma unroll
                    for (int j = 0; j < 4; ++j)
                        acc[i][j] = __builtin_amdgcn_mfma_f32_16x16x32_bf16(
                            a[i], b[j], acc[i][j], 0, 0, 0);
            }
        }
    }

    // epilogue: C/D layout col=lane&15, row=quad*4+reg  [m89-verified]
#pragma unroll
    for (int j = 0; j < 4; ++j) {
        int col = bn + wx * 64 + j * 16 + l16;
        float bv = (col < outN) ? bias[col] : 0.f;
#pragma unroll
        for (int i = 0; i < 4; ++i) {
            int rowBase = bm + wy * 64 + i * 16 + (quad << 2);
#pragma unroll
            for (int r = 0; r < 4; ++r) {
                int row = rowBase + r;
                if (row >= M) continue;
                float v = acc[i][j][r] + bv;
                if constexpr (OUT_BF16) {
                    float o = (col < outN) ? fmaxf(v, 0.f) : 0.f;  // zero k-pad for GEMM2
                    outB[(size_t)row * outStride + col] = __float2bfloat16(o);
                } else {
                    if (col < outN) outF[(size_t)row * outStride + col] = v;
                }
            }
        }
    }
}

// ---------- per-column sum / sumsq; grid*block stride multiple of C4 ----------
__global__ __launch_bounds__(256) void stats_kernel(
    const float* __restrict__ h, float* __restrict__ sum, float* __restrict__ sumsq,
    int total4)
{
    int idx = blockIdx.x * 256 + threadIdx.x;
    int stride = gridDim.x * 256;
    int c = (idx % C4) << 2;
    float s0 = 0, s1 = 0, s2 = 0, s3 = 0, q0 = 0, q1 = 0, q2 = 0, q3 = 0;
    const float4* h4 = (const float4*)h;
    for (int i = idx; i < total4; i += stride) {
        float4 v = h4[i];
        s0 += v.x; q0 += v.x * v.x;
        s1 += v.y; q1 += v.y * v.y;
        s2 += v.z; q2 += v.z * v.z;
        s3 += v.w; q3 += v.w * v.w;
    }
    atomicAdd(&sum[c + 0], s0); atomicAdd(&sumsq[c + 0], q0);
    atomicAdd(&sum[c + 1], s1); atomicAdd(&sumsq[c + 1], q1);
    atomicAdd(&sum[c + 2], s2); atomicAdd(&sumsq[c + 2], q2);
    atomicAdd(&sum[c + 3], s3); atomicAdd(&sumsq[c + 3], q3);
}

__global__ void finalize_kernel(
    const float* __restrict__ sum, const float* __restrict__ sumsq,
    const float* __restrict__ gamma, const float* __restrict__ beta,
    float* __restrict__ scale, float* __restrict__ shift, float inv_n)
{
    int c = threadIdx.x;
    if (c < DD) {
        float mu = sum[c] * inv_n;
        float var = sumsq[c] * inv_n - mu * mu;
        float inv = rsqrtf(var + BN_EPS);
        float sc = gamma[c] * inv;
        scale[c] = sc;
        shift[c] = fmaf(-mu, sc, beta[c]);
    }
}

// ---------- final: out = scale*h + shift (in-place on d_out) ----------
__global__ __launch_bounds__(256) void apply_kernel(
    const float* __restrict__ h, const float* __restrict__ scale,
    const float* __restrict__ shift, float* __restrict__ out, int total4)
{
    int i = blockIdx.x * 256 + threadIdx.x;
    if (i >= total4) return;
    int c = (i % C4) << 2;
    float4 v = ((const float4*)h)[i];
    float4 r;
    r.x = fmaf(scale[c + 0], v.x, shift[c + 0]);
    r.y = fmaf(scale[c + 1], v.y, shift[c + 1]);
    r.z = fmaf(scale[c + 2], v.z, shift[c + 2]);
    r.w = fmaf(scale[c + 3], v.w, shift[c + 3]);
    ((float4*)out)[i] = r;
}

extern "C" void kernel_launch(void* const* d_in, const int* in_sizes, int n_in,
                              void* d_out, int out_size, void* d_ws, size_t ws_size,
                              hipStream_t stream)
{
    const int*   x      = (const int*)d_in[0];
    const int*   ei     = (const int*)d_in[1];
    const int*   ea     = (const int*)d_in[2];
    const float* x_emb1 = (const float*)d_in[3];
    const float* x_emb2 = (const float*)d_in[4];
    const float* e_emb1 = (const float*)d_in[5];
    const float* e_emb2 = (const float*)d_in[6];
    const float* w1     = (const float*)d_in[7];
    const float* b1     = (const float*)d_in[8];
    const float* w2     = (const float*)d_in[9];
    const float* b2     = (const float*)d_in[10];
    const float* gamma  = (const float*)d_in[11];
    const float* beta   = (const float*)d_in[12];

    const int n = in_sizes[0] / 2;           // 100000
    const int E = in_sizes[1] / 2;           // 250000
    const int Mp = ((n + 127) / 128) * 128;  // 100096 (128-row block tiles)
    const int Kp1 = 320, Kp2 = 640;          // padded K (multiples of 64)
    const int NP1 = 640, NP2 = 384;          // padded output dims (tiles of 128)

    // ---- workspace layout ----
    char* p = (char*)d_ws;
    auto alloc = [&](size_t bytes) -> void* {
        void* r = (void*)p;
        p += (bytes + 255) & ~(size_t)255;
        return r;
    };
    __hip_bfloat16* aggH = (__hip_bfloat16*)alloc((size_t)Mp * Kp1 * 2);
    __hip_bfloat16* aggL = (__hip_bfloat16*)alloc((size_t)Mp * Kp1 * 2);
    __hip_bfloat16* hid  = (__hip_bfloat16*)alloc((size_t)Mp * Kp2 * 2);
    __hip_bfloat16* w1h  = (__hip_bfloat16*)alloc((size_t)5 * NP1 * Kp1 * 2);
    __hip_bfloat16* w1l  = (__hip_bfloat16*)alloc((size_t)5 * NP1 * Kp1 * 2);
    __hip_bfloat16* w2h  = (__hip_bfloat16*)alloc((size_t)5 * NP2 * Kp2 * 2);
    __hip_bfloat16* w2l  = (__hip_bfloat16*)alloc((size_t)5 * NP2 * Kp2 * 2);
    float* ec    = (float*)alloc((size_t)5 * 18 * DD * 4);
    int*   head  = (int*)alloc((size_t)n * 4);
    int2*  links = (int2*)alloc((size_t)E * 8);
    float* sum   = (float*)alloc(320 * 4);
    float* sumsq = (float*)alloc(320 * 4);
    float* scale = (float*)alloc(320 * 4);
    float* shift = (float*)alloc(320 * 4);

    float* h = (float*)d_out;            // h lives in d_out; final apply in-place
    const int total4 = n * C4;

    // ---- one-time (per call) prep ----
    {
        int t1 = 5 * NP1 * Kp1;
        convert_w_kernel<<<(t1 + 255) / 256, 256, 0, stream>>>(w1, w1h, w1l, 600, 300, NP1, Kp1);
        int t2 = 5 * NP2 * Kp2;
        convert_w_kernel<<<(t2 + 255) / 256, 256, 0, stream>>>(w2, w2h, w2l, 300, 600, NP2, Kp2);
        int t3 = 5 * 18 * DD;
        build_ec_kernel<<<(t3 + 255) / 256, 256, 0, stream>>>(e_emb1, e_emb2, ec);
        hipMemsetAsync(head, 0xFF, (size_t)n * 4, stream);   // head = -1
        build_links_kernel<<<(E + 255) / 256, 256, 0, stream>>>(ei, ea, head, links, E);
        embed_kernel<<<(total4 + 255) / 256, 256, 0, stream>>>(x, x_emb1, x_emb2, h, total4);
    }

    const int gatherTotal = n * 80;
    dim3 g1(NP1 / 128, Mp / 128);   // (5, 782)
    dim3 g2(NP2 / 128, Mp / 128);   // (3, 782)

    for (int l = 0; l < 5; l++) {
        hipMemsetAsync(sum, 0, 2 * 320 * sizeof(float), stream);  // sum+sumsq contiguous
        gather_kernel<<<(gatherTotal + 255) / 256, 256, 0, stream>>>(
            h, head, links, ec + (size_t)l * 18 * DD, scale, shift, l > 0 ? 1 : 0,
            aggH, aggL, n);
        // GEMM1: [aggH*w1h | aggL*w1h | aggH*w1l], Kseg=320 -> hid (bf16, relu, 640-wide)
        const __hip_bfloat16* w1hL = w1h + (size_t)l * NP1 * Kp1;
        const __hip_bfloat16* w1lL = w1l + (size_t)l * NP1 * Kp1;
        mfma_gemm_lds<3, true><<<g1, 256, 0, stream>>>(
            aggH, aggL, aggH, w1hL, w1hL, w1lL,
            b1 + (size_t)l * 600, hid, nullptr, n, Kp1, Kp2, 600);
        // GEMM2: [hid*w2h | hid*w2l], Kseg=640 -> h (fp32, 300-wide)
        const __hip_bfloat16* w2hL = w2h + (size_t)l * NP2 * Kp2;
        const __hip_bfloat16* w2lL = w2l + (size_t)l * NP2 * Kp2;
        mfma_gemm_lds<2, false><<<g2, 256, 0, stream>>>(
            hid, hid, nullptr, w2hL, w2lL, nullptr,
            b2 + (size_t)l * 300, nullptr, h, n, Kp2, 300, 300);
        stats_kernel<<<600, 256, 0, stream>>>(h, sum, sumsq, total4);
        finalize_kernel<<<1, 320, 0, stream>>>(sum, sumsq, gamma + (size_t)l * DD,
                                               beta + (size_t)l * DD, scale, shift,
                                               1.0f / (float)n);
    }
    apply_kernel<<<(total4 + 255) / 256, 256, 0, stream>>>(h, scale, shift, h, total4);
}

// Round 4
// 2988.890 us; speedup vs baseline: 5.9010x; 1.3681x over previous
//
#include <hip/hip_runtime.h>
#include <hip/hip_bf16.h>

#define DD 300        // EMB
#define C4 75         // DD/4 float4 chunks per row
#define BN_EPS 1e-5f

typedef _Float16 f16x8 __attribute__((ext_vector_type(8)));   // 8 fp16 in 4 VGPRs
typedef float f32x4 __attribute__((ext_vector_type(4)));

union PackH4 { _Float16 h[4]; uint2 u; };

// async global->LDS, 16 B per lane, dest = wave-uniform base + lane*16
__device__ __forceinline__ void gld_lds16(const void* g, void* lds) {
    __builtin_amdgcn_global_load_lds(
        (const __attribute__((address_space(1))) void*)g,
        (__attribute__((address_space(3))) void*)lds, 16, 0, 0);
}

// ---------- h0 = x_emb1[x[:,0]] + x_emb2[x[:,1]] ----------
__global__ __launch_bounds__(256) void embed_kernel(
    const int* __restrict__ x, const float* __restrict__ emb1,
    const float* __restrict__ emb2, float* __restrict__ h, int total4)
{
    int i = blockIdx.x * 256 + threadIdx.x;
    if (i >= total4) return;
    int node = i / C4, chunk = i - node * C4;
    int a = x[2 * node], b = x[2 * node + 1];
    int c = chunk << 2;
    float4 v1 = *(const float4*)(emb1 + (size_t)a * DD + c);
    float4 v2 = *(const float4*)(emb2 + (size_t)b * DD + c);
    float4 r;
    r.x = v1.x + v2.x; r.y = v1.y + v2.y; r.z = v1.z + v2.z; r.w = v1.w + v2.w;
    *(float4*)(h + (size_t)node * DD + c) = r;
}

// ---------- combined edge-embedding table: ec[l][a0*3+a1][c] ----------
__global__ __launch_bounds__(256) void build_ec_kernel(
    const float* __restrict__ e1, const float* __restrict__ e2, float* __restrict__ ec)
{
    int gid = blockIdx.x * 256 + threadIdx.x;
    if (gid >= 5 * 18 * DD) return;
    int l = gid / (18 * DD);
    int rem = gid - l * 18 * DD;
    int combo = rem / DD;
    int c = rem - combo * DD;
    int a0 = combo / 3, a1 = combo - a0 * 3;
    ec[gid] = e1[(size_t)l * 6 * DD + a0 * DD + c] + e2[(size_t)l * 3 * DD + a1 * DD + c];
}

// ---------- per-dst linked list: head[dst] -> chain of edges ----------
__global__ __launch_bounds__(256) void build_links_kernel(
    const int* __restrict__ ei, const int* __restrict__ ea,
    int* __restrict__ head, int2* __restrict__ links, int E)
{
    int e = blockIdx.x * 256 + threadIdx.x;
    if (e >= E) return;
    int src = ei[e];
    int dst = ei[E + e];
    int combo = ea[2 * e] * 3 + ea[2 * e + 1];
    int old = atomicExch(&head[dst], e);
    links[e] = make_int2(old, src | (combo << 18));
}

// ---------- gather: agg[i] = sum over in-edges of affine(h[src]) + ec[combo], + self ----------
// output: fp16, K padded to 320 (chunks 75..79 zeroed)
__global__ __launch_bounds__(256) void gather_kernel(
    const float* __restrict__ h, const int* __restrict__ head,
    const int2* __restrict__ links, const float* __restrict__ ec,
    const float* __restrict__ scale, const float* __restrict__ shift, int use_affine,
    _Float16* __restrict__ agg, int n)
{
    int gid = blockIdx.x * 256 + threadIdx.x;
    int node = gid / 80, ch = gid - node * 80;
    if (node >= n) return;
    size_t obase = (size_t)node * 320 + (ch << 2);
    if (ch >= 75) {  // zero the k-pad columns 300..319
        *(uint2*)(agg + obase) = make_uint2(0u, 0u);
        return;
    }
    int c = ch << 2;
    float4 sc, sh;
    if (use_affine) {
        sc = *(const float4*)(scale + c);
        sh = *(const float4*)(shift + c);
    }
    float4 acc = *(const float4*)(h + (size_t)node * DD + c);  // self-loop, combo 12
    if (use_affine) {
        acc.x = fmaxf(fmaf(sc.x, acc.x, sh.x), 0.f);
        acc.y = fmaxf(fmaf(sc.y, acc.y, sh.y), 0.f);
        acc.z = fmaxf(fmaf(sc.z, acc.z, sh.z), 0.f);
        acc.w = fmaxf(fmaf(sc.w, acc.w, sh.w), 0.f);
    }
    float4 es = *(const float4*)(ec + 12 * DD + c);
    acc.x += es.x; acc.y += es.y; acc.z += es.z; acc.w += es.w;

    for (int e = head[node]; e >= 0; ) {
        int2 lk = links[e];
        e = lk.x;
        int src = lk.y & 0x3FFFF;
        int combo = lk.y >> 18;
        float4 hv = *(const float4*)(h + (size_t)src * DD + c);
        if (use_affine) {
            hv.x = fmaxf(fmaf(sc.x, hv.x, sh.x), 0.f);
            hv.y = fmaxf(fmaf(sc.y, hv.y, sh.y), 0.f);
            hv.z = fmaxf(fmaf(sc.z, hv.z, sh.z), 0.f);
            hv.w = fmaxf(fmaf(sc.w, hv.w, sh.w), 0.f);
        }
        float4 ev = *(const float4*)(ec + combo * DD + c);
        acc.x += hv.x + ev.x;
        acc.y += hv.y + ev.y;
        acc.z += hv.z + ev.z;
        acc.w += hv.w + ev.w;
    }
    PackH4 p;
    p.h[0] = (_Float16)acc.x;
    p.h[1] = (_Float16)acc.y;
    p.h[2] = (_Float16)acc.z;
    p.h[3] = (_Float16)acc.w;
    *(uint2*)(agg + obase) = p.u;
}

// ---------- convert fp32 weights (out,in) -> padded fp16 ----------
__global__ __launch_bounds__(256) void convert_w_kernel(
    const float* __restrict__ w, _Float16* __restrict__ wf,
    int rows, int cols, int rowsP, int colsP)
{
    int gid = blockIdx.x * 256 + threadIdx.x;
    int total = 5 * rowsP * colsP;
    if (gid >= total) return;
    int l = gid / (rowsP * colsP);
    int rem = gid - l * rowsP * colsP;
    int r = rem / colsP;
    int k = rem - r * colsP;
    float v = (r < rows && k < cols) ? w[((size_t)l * rows + r) * cols + k] : 0.f;
    wf[gid] = (_Float16)v;
}

// ---------- LDS-staged fp16 MFMA GEMM ----------
// C = act(A @ W^T + bias),  A:[MpA,Kp] fp16, W:[NP,Kp] fp16 (rows = output cols)
// block 256 thr = 4 waves (2x2), block tile 128m x 128n, wave tile 64x64
// 1-D grid, XCD-aware decode: 8 consecutive blocks = 8 row tiles of one col tile,
// so all col tiles of a row tile land on the same XCD -> A slice stays in that L2.
template <bool OUT_F16>
__global__ __launch_bounds__(256) void mfma_gemm_lds(
    const _Float16* __restrict__ A, const _Float16* __restrict__ W,
    const float* __restrict__ bias,
    _Float16* __restrict__ outH, float* __restrict__ outF,
    int M, int Kp, int outStride, int outN, int nCol)
{
    __shared__ __attribute__((aligned(16))) unsigned short sA[128 * 64];
    __shared__ __attribute__((aligned(16))) unsigned short sB[128 * 64];

    const int bid = blockIdx.x;
    const int group = bid / (8 * nCol);
    const int within = bid - group * 8 * nCol;
    const int rowT = group * 8 + (within & 7);
    const int colT = within >> 3;
    const int bm = rowT << 7;
    const int bn = colT << 7;

    const int tid = threadIdx.x;
    const int lane = tid & 63, wv = tid >> 6;
    const int wy = wv & 1, wx = wv >> 1;            // 2x2 wave grid
    const int quad = lane >> 4, l16 = lane & 15;

    // staging: call j stages rows wv*32+j*8 .. +7; 8 lanes/row, swizzled chunk
    const int r8 = lane >> 3;                        // 0..7 row within call
    const int chv = (lane & 7) ^ r8;                 // swizzled chunk to fetch

    f32x4 acc[4][4] = {};

    for (int k0 = 0; k0 < Kp; k0 += 64) {
        __syncthreads();   // previous iter's ds_reads done before overwrite
#pragma unroll
        for (int j = 0; j < 4; ++j) {
            int rloc = wv * 32 + j * 8 + r8;
            int ldsBase = (wv * 32 + j * 8) * 64;
            gld_lds16(A + (size_t)(bm + rloc) * Kp + k0 + chv * 8, &sA[ldsBase]);
            gld_lds16(W + (size_t)(bn + rloc) * Kp + k0 + chv * 8, &sB[ldsBase]);
        }
        __syncthreads();   // drain global_load_lds
#pragma unroll
        for (int kk = 0; kk < 2; ++kk) {
            f16x8 a[4], b[4];
#pragma unroll
            for (int i = 0; i < 4; ++i) {
                int rA = wy * 64 + i * 16 + l16;
                int slotA = (kk * 4 + quad) ^ (rA & 7);
                a[i] = *(const f16x8*)&sA[rA * 64 + slotA * 8];
                int rB = wx * 64 + i * 16 + l16;
                int slotB = (kk * 4 + quad) ^ (rB & 7);
                b[i] = *(const f16x8*)&sB[rB * 64 + slotB * 8];
            }
#pragma unroll
            for (int i = 0; i < 4; ++i)
#pragma unroll
                for (int j = 0; j < 4; ++j)
                    acc[i][j] = __builtin_amdgcn_mfma_f32_16x16x32_f16(
                        a[i], b[j], acc[i][j], 0, 0, 0);
        }
    }

    // epilogue: C/D layout col=lane&15, row=quad*4+reg  [m89-verified]
#pragma unroll
    for (int j = 0; j < 4; ++j) {
        int col = bn + wx * 64 + j * 16 + l16;
        float bv = (col < outN) ? bias[col] : 0.f;
#pragma unroll
        for (int i = 0; i < 4; ++i) {
            int rowBase = bm + wy * 64 + i * 16 + (quad << 2);
#pragma unroll
            for (int r = 0; r < 4; ++r) {
                int row = rowBase + r;
                if (row >= M) continue;
                float v = acc[i][j][r] + bv;
                if constexpr (OUT_F16) {
                    float o = (col < outN) ? fmaxf(v, 0.f) : 0.f;  // relu + zero k-pad
                    outH[(size_t)row * outStride + col] = (_Float16)o;
                } else {
                    if (col < outN) outF[(size_t)row * outStride + col] = v;
                }
            }
        }
    }
}

// ---------- per-column sum / sumsq; grid*block stride multiple of C4 ----------
__global__ __launch_bounds__(256) void stats_kernel(
    const float* __restrict__ h, float* __restrict__ sum, float* __restrict__ sumsq,
    int total4)
{
    int idx = blockIdx.x * 256 + threadIdx.x;
    int stride = gridDim.x * 256;
    int c = (idx % C4) << 2;
    float s0 = 0, s1 = 0, s2 = 0, s3 = 0, q0 = 0, q1 = 0, q2 = 0, q3 = 0;
    const float4* h4 = (const float4*)h;
    for (int i = idx; i < total4; i += stride) {
        float4 v = h4[i];
        s0 += v.x; q0 += v.x * v.x;
        s1 += v.y; q1 += v.y * v.y;
        s2 += v.z; q2 += v.z * v.z;
        s3 += v.w; q3 += v.w * v.w;
    }
    atomicAdd(&sum[c + 0], s0); atomicAdd(&sumsq[c + 0], q0);
    atomicAdd(&sum[c + 1], s1); atomicAdd(&sumsq[c + 1], q1);
    atomicAdd(&sum[c + 2], s2); atomicAdd(&sumsq[c + 2], q2);
    atomicAdd(&sum[c + 3], s3); atomicAdd(&sumsq[c + 3], q3);
}

__global__ void finalize_kernel(
    const float* __restrict__ sum, const float* __restrict__ sumsq,
    const float* __restrict__ gamma, const float* __restrict__ beta,
    float* __restrict__ scale, float* __restrict__ shift, float inv_n)
{
    int c = threadIdx.x;
    if (c < DD) {
        float mu = sum[c] * inv_n;
        float var = sumsq[c] * inv_n - mu * mu;
        float inv = rsqrtf(var + BN_EPS);
        float sc = gamma[c] * inv;
        scale[c] = sc;
        shift[c] = fmaf(-mu, sc, beta[c]);
    }
}

// ---------- final: out = scale*h + shift (in-place on d_out) ----------
__global__ __launch_bounds__(256) void apply_kernel(
    const float* __restrict__ h, const float* __restrict__ scale,
    const float* __restrict__ shift, float* __restrict__ out, int total4)
{
    int i = blockIdx.x * 256 + threadIdx.x;
    if (i >= total4) return;
    int c = (i % C4) << 2;
    float4 v = ((const float4*)h)[i];
    float4 r;
    r.x = fmaf(scale[c + 0], v.x, shift[c + 0]);
    r.y = fmaf(scale[c + 1], v.y, shift[c + 1]);
    r.z = fmaf(scale[c + 2], v.z, shift[c + 2]);
    r.w = fmaf(scale[c + 3], v.w, shift[c + 3]);
    ((float4*)out)[i] = r;
}

extern "C" void kernel_launch(void* const* d_in, const int* in_sizes, int n_in,
                              void* d_out, int out_size, void* d_ws, size_t ws_size,
                              hipStream_t stream)
{
    const int*   x      = (const int*)d_in[0];
    const int*   ei     = (const int*)d_in[1];
    const int*   ea     = (const int*)d_in[2];
    const float* x_emb1 = (const float*)d_in[3];
    const float* x_emb2 = (const float*)d_in[4];
    const float* e_emb1 = (const float*)d_in[5];
    const float* e_emb2 = (const float*)d_in[6];
    const float* w1     = (const float*)d_in[7];
    const float* b1     = (const float*)d_in[8];
    const float* w2     = (const float*)d_in[9];
    const float* b2     = (const float*)d_in[10];
    const float* gamma  = (const float*)d_in[11];
    const float* beta   = (const float*)d_in[12];

    const int n = in_sizes[0] / 2;           // 100000
    const int E = in_sizes[1] / 2;           // 250000
    const int nRowT = (n + 127) / 128;       // 782 row tiles
    const int nRowTP = ((nRowT + 7) / 8) * 8;     // 784 (multiple of 8 for swizzle)
    const int MpA = nRowTP * 128;            // 100352 padded rows
    const int Kp1 = 320, Kp2 = 640;          // padded K (multiples of 64)
    const int NP1 = 640, NP2 = 384;          // padded output dims (tiles of 128)

    // ---- workspace layout ----
    char* p = (char*)d_ws;
    auto alloc = [&](size_t bytes) -> void* {
        void* r = (void*)p;
        p += (bytes + 255) & ~(size_t)255;
        return r;
    };
    _Float16* agg  = (_Float16*)alloc((size_t)MpA * Kp1 * 2);
    _Float16* hid  = (_Float16*)alloc((size_t)MpA * Kp2 * 2);
    _Float16* w1f  = (_Float16*)alloc((size_t)5 * NP1 * Kp1 * 2);
    _Float16* w2f  = (_Float16*)alloc((size_t)5 * NP2 * Kp2 * 2);
    float* ec    = (float*)alloc((size_t)5 * 18 * DD * 4);
    int*   head  = (int*)alloc((size_t)n * 4);
    int2*  links = (int2*)alloc((size_t)E * 8);
    float* sum   = (float*)alloc(320 * 4);
    float* sumsq = (float*)alloc(320 * 4);
    float* scale = (float*)alloc(320 * 4);
    float* shift = (float*)alloc(320 * 4);

    float* h = (float*)d_out;            // h lives in d_out; final apply in-place
    const int total4 = n * C4;

    // ---- one-time (per call) prep ----
    {
        int t1 = 5 * NP1 * Kp1;
        convert_w_kernel<<<(t1 + 255) / 256, 256, 0, stream>>>(w1, w1f, 600, 300, NP1, Kp1);
        int t2 = 5 * NP2 * Kp2;
        convert_w_kernel<<<(t2 + 255) / 256, 256, 0, stream>>>(w2, w2f, 300, 600, NP2, Kp2);
        int t3 = 5 * 18 * DD;
        build_ec_kernel<<<(t3 + 255) / 256, 256, 0, stream>>>(e_emb1, e_emb2, ec);
        hipMemsetAsync(head, 0xFF, (size_t)n * 4, stream);   // head = -1
        build_links_kernel<<<(E + 255) / 256, 256, 0, stream>>>(ei, ea, head, links, E);
        embed_kernel<<<(total4 + 255) / 256, 256, 0, stream>>>(x, x_emb1, x_emb2, h, total4);
    }

    const int gatherTotal = n * 80;
    const int nCol1 = NP1 / 128;   // 5
    const int nCol2 = NP2 / 128;   // 3
    const int g1 = nRowTP * nCol1; // 3920 blocks
    const int g2 = nRowTP * nCol2; // 2352 blocks

    for (int l = 0; l < 5; l++) {
        hipMemsetAsync(sum, 0, 2 * 320 * sizeof(float), stream);  // sum+sumsq contiguous
        gather_kernel<<<(gatherTotal + 255) / 256, 256, 0, stream>>>(
            h, head, links, ec + (size_t)l * 18 * DD, scale, shift, l > 0 ? 1 : 0,
            agg, n);
        // GEMM1: agg[Mp,320] x w1[640,320] -> hid fp16 (relu, stride 640)
        mfma_gemm_lds<true><<<g1, 256, 0, stream>>>(
            agg, w1f + (size_t)l * NP1 * Kp1,
            b1 + (size_t)l * 600, hid, nullptr, n, Kp1, Kp2, 600, nCol1);
        // GEMM2: hid[Mp,640] x w2[384,640] -> h fp32 (stride 300)
        mfma_gemm_lds<false><<<g2, 256, 0, stream>>>(
            hid, w2f + (size_t)l * NP2 * Kp2,
            b2 + (size_t)l * 300, nullptr, h, n, Kp2, 300, 300, nCol2);
        stats_kernel<<<600, 256, 0, stream>>>(h, sum, sumsq, total4);
        finalize_kernel<<<1, 320, 0, stream>>>(sum, sumsq, gamma + (size_t)l * DD,
                                               beta + (size_t)l * DD, scale, shift,
                                               1.0f / (float)n);
    }
    apply_kernel<<<(total4 + 255) / 256, 256, 0, stream>>>(h, scale, shift, h, total4);
}

// Round 5
// 1948.658 us; speedup vs baseline: 9.0510x; 1.5338x over previous
//
#include <hip/hip_runtime.h>
#include <hip/hip_bf16.h>

#define DD 300        // EMB
#define C4 75         // DD/4 float4 chunks per row
#define BN_EPS 1e-5f

typedef _Float16 f16x8 __attribute__((ext_vector_type(8)));   // 8 fp16 in 4 VGPRs
typedef float f32x4 __attribute__((ext_vector_type(4)));

union PackH4 { _Float16 h[4]; uint2 u; };

// async global->LDS, 16 B per lane, dest = wave-uniform base + lane*16
__device__ __forceinline__ void gld_lds16(const void* g, void* lds) {
    __builtin_amdgcn_global_load_lds(
        (const __attribute__((address_space(1))) void*)g,
        (__attribute__((address_space(3))) void*)lds, 16, 0, 0);
}

// ---------- h0 = x_emb1[x[:,0]] + x_emb2[x[:,1]] ----------
__global__ __launch_bounds__(256) void embed_kernel(
    const int* __restrict__ x, const float* __restrict__ emb1,
    const float* __restrict__ emb2, float* __restrict__ h, int total4)
{
    int i = blockIdx.x * 256 + threadIdx.x;
    if (i >= total4) return;
    int node = i / C4, chunk = i - node * C4;
    int a = x[2 * node], b = x[2 * node + 1];
    int c = chunk << 2;
    float4 v1 = *(const float4*)(emb1 + (size_t)a * DD + c);
    float4 v2 = *(const float4*)(emb2 + (size_t)b * DD + c);
    float4 r;
    r.x = v1.x + v2.x; r.y = v1.y + v2.y; r.z = v1.z + v2.z; r.w = v1.w + v2.w;
    *(float4*)(h + (size_t)node * DD + c) = r;
}

// ---------- combined edge-embedding table: ec[l][a0*3+a1][c] ----------
__global__ __launch_bounds__(256) void build_ec_kernel(
    const float* __restrict__ e1, const float* __restrict__ e2, float* __restrict__ ec)
{
    int gid = blockIdx.x * 256 + threadIdx.x;
    if (gid >= 5 * 18 * DD) return;
    int l = gid / (18 * DD);
    int rem = gid - l * 18 * DD;
    int combo = rem / DD;
    int c = rem - combo * DD;
    int a0 = combo / 3, a1 = combo - a0 * 3;
    ec[gid] = e1[(size_t)l * 6 * DD + a0 * DD + c] + e2[(size_t)l * 3 * DD + a1 * DD + c];
}

// ================= CSR build =================
__global__ __launch_bounds__(256) void deg_kernel(
    const int* __restrict__ ei, int* __restrict__ deg, int E)
{
    int e = blockIdx.x * 256 + threadIdx.x;
    if (e >= E) return;
    atomicAdd(&deg[ei[E + e]], 1);
}

// block scans 1024 elements (4/thread); writes local-exclusive prefix + block total
__global__ __launch_bounds__(256) void scan1_kernel(
    const int* __restrict__ deg, int* __restrict__ pre, int* __restrict__ blockSum, int n)
{
    __shared__ int sa[256], sb[256];
    int t = threadIdx.x;
    int base = blockIdx.x * 1024 + t * 4;
    int v0 = (base + 0 < n) ? deg[base + 0] : 0;
    int v1 = (base + 1 < n) ? deg[base + 1] : 0;
    int v2 = (base + 2 < n) ? deg[base + 2] : 0;
    int v3 = (base + 3 < n) ? deg[base + 3] : 0;
    int tot = v0 + v1 + v2 + v3;
    sa[t] = tot;
    __syncthreads();
    int* src = sa; int* dst = sb;
    for (int off = 1; off < 256; off <<= 1) {
        int v = src[t];
        if (t >= off) v += src[t - off];
        dst[t] = v;
        __syncthreads();
        int* tmp = src; src = dst; dst = tmp;
    }
    int incl = src[t];
    int excl = incl - tot;
    if (base + 0 < n) pre[base + 0] = excl;
    if (base + 1 < n) pre[base + 1] = excl + v0;
    if (base + 2 < n) pre[base + 2] = excl + v0 + v1;
    if (base + 3 < n) pre[base + 3] = excl + v0 + v1 + v2;
    if (t == 255) blockSum[blockIdx.x] = incl;
}

// single-block exclusive scan of blockSum (nb <= 256)
__global__ __launch_bounds__(256) void scan2_kernel(int* __restrict__ blockSum, int nb)
{
    __shared__ int sa[256], sb[256];
    int t = threadIdx.x;
    int v = (t < nb) ? blockSum[t] : 0;
    sa[t] = v;
    __syncthreads();
    int* src = sa; int* dst = sb;
    for (int off = 1; off < 256; off <<= 1) {
        int x = src[t];
        if (t >= off) x += src[t - off];
        dst[t] = x;
        __syncthreads();
        int* tmp = src; src = dst; dst = tmp;
    }
    if (t < nb) blockSum[t] = src[t] - v;   // exclusive
}

// rowPtr[idx] = pre[idx] + blockSum[idx/1024]; rowPtr[n] = E; cursor = rowPtr
__global__ __launch_bounds__(256) void scan3_kernel(
    const int* __restrict__ pre, const int* __restrict__ blockSum,
    int* __restrict__ rowPtr, int* __restrict__ cursor, int n, int E)
{
    int idx = blockIdx.x * 256 + threadIdx.x;
    if (idx > n) return;
    int v = (idx < n) ? pre[idx] + blockSum[idx >> 10] : E;
    rowPtr[idx] = v;
    if (idx < n) cursor[idx] = v;
}

__global__ __launch_bounds__(256) void fill_kernel(
    const int* __restrict__ ei, const int* __restrict__ ea,
    int* __restrict__ cursor, int* __restrict__ edges, int E)
{
    int e = blockIdx.x * 256 + threadIdx.x;
    if (e >= E) return;
    int src = ei[e];
    int dst = ei[E + e];
    int combo = ea[2 * e] * 3 + ea[2 * e + 1];
    int slot = atomicAdd(&cursor[dst], 1);
    edges[slot] = src | (combo << 18);
}

// ---------- gather (CSR): agg[i] = self + sum_e affine(h[src]) + ec[combo] ----------
// agg pads (cols>=300, rows>=n) pre-zeroed once in prep
__global__ __launch_bounds__(256) void gather_kernel(
    const float* __restrict__ h, const int* __restrict__ rowPtr,
    const int* __restrict__ edges, const float* __restrict__ ec,
    const float* __restrict__ scale, const float* __restrict__ shift, int use_affine,
    _Float16* __restrict__ agg, int n)
{
    int gid = blockIdx.x * 256 + threadIdx.x;
    int node = gid / C4, ch = gid - node * C4;
    if (node >= n) return;
    int c = ch << 2;
    float4 sc, sh;
    if (use_affine) {
        sc = *(const float4*)(scale + c);
        sh = *(const float4*)(shift + c);
    }
    float4 acc = *(const float4*)(h + (size_t)node * DD + c);  // self-loop, combo 12
    if (use_affine) {
        acc.x = fmaxf(fmaf(sc.x, acc.x, sh.x), 0.f);
        acc.y = fmaxf(fmaf(sc.y, acc.y, sh.y), 0.f);
        acc.z = fmaxf(fmaf(sc.z, acc.z, sh.z), 0.f);
        acc.w = fmaxf(fmaf(sc.w, acc.w, sh.w), 0.f);
    }
    float4 es = *(const float4*)(ec + 12 * DD + c);
    acc.x += es.x; acc.y += es.y; acc.z += es.z; acc.w += es.w;

    int start = rowPtr[node], end = rowPtr[node + 1];
    for (int e = start; e < end; ++e) {
        int pk = edges[e];
        int src = pk & 0x3FFFF;
        int combo = pk >> 18;
        float4 hv = *(const float4*)(h + (size_t)src * DD + c);
        if (use_affine) {
            hv.x = fmaxf(fmaf(sc.x, hv.x, sh.x), 0.f);
            hv.y = fmaxf(fmaf(sc.y, hv.y, sh.y), 0.f);
            hv.z = fmaxf(fmaf(sc.z, hv.z, sh.z), 0.f);
            hv.w = fmaxf(fmaf(sc.w, hv.w, sh.w), 0.f);
        }
        float4 ev = *(const float4*)(ec + combo * DD + c);
        acc.x += hv.x + ev.x;
        acc.y += hv.y + ev.y;
        acc.z += hv.z + ev.z;
        acc.w += hv.w + ev.w;
    }
    PackH4 p;
    p.h[0] = (_Float16)acc.x;
    p.h[1] = (_Float16)acc.y;
    p.h[2] = (_Float16)acc.z;
    p.h[3] = (_Float16)acc.w;
    *(uint2*)(agg + (size_t)node * 320 + c) = p.u;
}

// ---------- convert fp32 weights (out,in) -> padded fp16 ----------
__global__ __launch_bounds__(256) void convert_w_kernel(
    const float* __restrict__ w, _Float16* __restrict__ wf,
    int rows, int cols, int rowsP, int colsP)
{
    int gid = blockIdx.x * 256 + threadIdx.x;
    int total = 5 * rowsP * colsP;
    if (gid >= total) return;
    int l = gid / (rowsP * colsP);
    int rem = gid - l * (rowsP * colsP);
    int r = rem / colsP;
    int k = rem - r * colsP;
    float v = (r < rows && k < cols) ? w[((size_t)l * rows + r) * cols + k] : 0.f;
    wf[gid] = (_Float16)v;
}

// ---------- LDS-staged fp16 MFMA GEMM (optional fused BN-stats) ----------
// C = act(A @ W^T + bias); 1-D grid, XCD-aware decode (8 row tiles per col tile group)
template <bool OUT_F16, bool DO_STATS>
__global__ __launch_bounds__(256) void mfma_gemm_lds(
    const _Float16* __restrict__ A, const _Float16* __restrict__ W,
    const float* __restrict__ bias,
    _Float16* __restrict__ outH, float* __restrict__ outF,
    float* __restrict__ sum, float* __restrict__ sumsq,
    int M, int Kp, int outStride, int outN, int nCol)
{
    __shared__ __attribute__((aligned(16))) unsigned short sA[128 * 64];
    __shared__ __attribute__((aligned(16))) unsigned short sB[128 * 64];

    const int bid = blockIdx.x;
    const int group = bid / (8 * nCol);
    const int within = bid - group * 8 * nCol;
    const int rowT = group * 8 + (within & 7);
    const int colT = within >> 3;
    const int bm = rowT << 7;
    const int bn = colT << 7;

    const int tid = threadIdx.x;
    const int lane = tid & 63, wv = tid >> 6;
    const int wy = wv & 1, wx = wv >> 1;            // 2x2 wave grid
    const int quad = lane >> 4, l16 = lane & 15;

    const int r8 = lane >> 3;                        // staging row within call
    const int chv = (lane & 7) ^ r8;                 // swizzled chunk to fetch

    f32x4 acc[4][4] = {};

    for (int k0 = 0; k0 < Kp; k0 += 64) {
        __syncthreads();
#pragma unroll
        for (int j = 0; j < 4; ++j) {
            int rloc = wv * 32 + j * 8 + r8;
            int ldsBase = (wv * 32 + j * 8) * 64;
            gld_lds16(A + (size_t)(bm + rloc) * Kp + k0 + chv * 8, &sA[ldsBase]);
            gld_lds16(W + (size_t)(bn + rloc) * Kp + k0 + chv * 8, &sB[ldsBase]);
        }
        __syncthreads();
#pragma unroll
        for (int kk = 0; kk < 2; ++kk) {
            f16x8 a[4], b[4];
#pragma unroll
            for (int i = 0; i < 4; ++i) {
                int rA = wy * 64 + i * 16 + l16;
                int slotA = (kk * 4 + quad) ^ (rA & 7);
                a[i] = *(const f16x8*)&sA[rA * 64 + slotA * 8];
                int rB = wx * 64 + i * 16 + l16;
                int slotB = (kk * 4 + quad) ^ (rB & 7);
                b[i] = *(const f16x8*)&sB[rB * 64 + slotB * 8];
            }
#pragma unroll
            for (int i = 0; i < 4; ++i)
#pragma unroll
                for (int j = 0; j < 4; ++j)
                    acc[i][j] = __builtin_amdgcn_mfma_f32_16x16x32_f16(
                        a[i], b[j], acc[i][j], 0, 0, 0);
        }
    }

    // epilogue: C/D layout col=lane&15, row=quad*4+reg  [m89-verified]
#pragma unroll
    for (int j = 0; j < 4; ++j) {
        int col = bn + wx * 64 + j * 16 + l16;
        float bv = (col < outN) ? bias[col] : 0.f;
        float cs = 0.f, cq = 0.f;   // per-lane column partial (rows of this wave half)
#pragma unroll
        for (int i = 0; i < 4; ++i) {
            int rowBase = bm + wy * 64 + i * 16 + (quad << 2);
#pragma unroll
            for (int r = 0; r < 4; ++r) {
                int row = rowBase + r;
                if (row >= M) continue;
                float v = acc[i][j][r] + bv;
                if constexpr (DO_STATS) { cs += v; cq += v * v; }
                if constexpr (OUT_F16) {
                    float o = (col < outN) ? fmaxf(v, 0.f) : 0.f;  // relu + zero k-pad
                    outH[(size_t)row * outStride + col] = (_Float16)o;
                } else {
                    if (col < outN) outF[(size_t)row * outStride + col] = v;
                }
            }
        }
        if constexpr (DO_STATS) {
            // reduce across quads: lanes l, l+16, l+32, l+48 hold same column
            cs += __shfl_down(cs, 32); cq += __shfl_down(cq, 32);
            cs += __shfl_down(cs, 16); cq += __shfl_down(cq, 16);
            if (quad == 0 && col < outN) {
                atomicAdd(&sum[col], cs);
                atomicAdd(&sumsq[col], cq);
            }
        }
    }
}

__global__ void finalize_kernel(
    const float* __restrict__ sum, const float* __restrict__ sumsq,
    const float* __restrict__ gamma, const float* __restrict__ beta,
    float* __restrict__ scale, float* __restrict__ shift, float inv_n)
{
    int c = threadIdx.x;
    if (c < DD) {
        float mu = sum[c] * inv_n;
        float var = sumsq[c] * inv_n - mu * mu;
        float inv = rsqrtf(var + BN_EPS);
        float sc = gamma[c] * inv;
        scale[c] = sc;
        shift[c] = fmaf(-mu, sc, beta[c]);
    }
}

// ---------- final: out = scale*h + shift (in-place on d_out) ----------
__global__ __launch_bounds__(256) void apply_kernel(
    const float* __restrict__ h, const float* __restrict__ scale,
    const float* __restrict__ shift, float* __restrict__ out, int total4)
{
    int i = blockIdx.x * 256 + threadIdx.x;
    if (i >= total4) return;
    int c = (i % C4) << 2;
    float4 v = ((const float4*)h)[i];
    float4 r;
    r.x = fmaf(scale[c + 0], v.x, shift[c + 0]);
    r.y = fmaf(scale[c + 1], v.y, shift[c + 1]);
    r.z = fmaf(scale[c + 2], v.z, shift[c + 2]);
    r.w = fmaf(scale[c + 3], v.w, shift[c + 3]);
    ((float4*)out)[i] = r;
}

extern "C" void kernel_launch(void* const* d_in, const int* in_sizes, int n_in,
                              void* d_out, int out_size, void* d_ws, size_t ws_size,
                              hipStream_t stream)
{
    const int*   x      = (const int*)d_in[0];
    const int*   ei     = (const int*)d_in[1];
    const int*   ea     = (const int*)d_in[2];
    const float* x_emb1 = (const float*)d_in[3];
    const float* x_emb2 = (const float*)d_in[4];
    const float* e_emb1 = (const float*)d_in[5];
    const float* e_emb2 = (const float*)d_in[6];
    const float* w1     = (const float*)d_in[7];
    const float* b1     = (const float*)d_in[8];
    const float* w2     = (const float*)d_in[9];
    const float* b2     = (const float*)d_in[10];
    const float* gamma  = (const float*)d_in[11];
    const float* beta   = (const float*)d_in[12];

    const int n = in_sizes[0] / 2;           // 100000
    const int E = in_sizes[1] / 2;           // 250000
    const int nRowT = (n + 127) / 128;       // 782 row tiles
    const int nRowTP = ((nRowT + 7) / 8) * 8;     // 784 (multiple of 8 for swizzle)
    const int MpA = nRowTP * 128;            // 100352 padded rows
    const int Kp1 = 320, Kp2 = 640;          // padded K (multiples of 64)
    const int NP1 = 640, NP2 = 384;          // padded output dims (tiles of 128)

    // ---- workspace layout ----
    char* p = (char*)d_ws;
    auto alloc = [&](size_t bytes) -> void* {
        void* r = (void*)p;
        p += (bytes + 255) & ~(size_t)255;
        return r;
    };
    _Float16* agg  = (_Float16*)alloc((size_t)MpA * Kp1 * 2);
    _Float16* hid  = (_Float16*)alloc((size_t)MpA * Kp2 * 2);
    _Float16* w1f  = (_Float16*)alloc((size_t)5 * NP1 * Kp1 * 2);
    _Float16* w2f  = (_Float16*)alloc((size_t)5 * NP2 * Kp2 * 2);
    float* ec     = (float*)alloc((size_t)5 * 18 * DD * 4);
    int*   deg    = (int*)alloc((size_t)n * 4);
    int*   rowPtr = (int*)alloc((size_t)(n + 1) * 4);
    int*   cursor = (int*)alloc((size_t)n * 4);
    int*   blockSum = (int*)alloc(256 * 4);
    int*   edges  = (int*)alloc((size_t)E * 4);
    float* sum   = (float*)alloc(320 * 4);
    float* sumsq = (float*)alloc(320 * 4);
    float* scale = (float*)alloc(320 * 4);
    float* shift = (float*)alloc(320 * 4);

    float* h = (float*)d_out;            // h lives in d_out; final apply in-place
    const int total4 = n * C4;
    const int nb = (n + 1023) / 1024;    // scan blocks (98)

    // ---- one-time (per call) prep ----
    {
        convert_w_kernel<<<(5 * NP1 * Kp1 + 255) / 256, 256, 0, stream>>>(w1, w1f, 600, 300, NP1, Kp1);
        convert_w_kernel<<<(5 * NP2 * Kp2 + 255) / 256, 256, 0, stream>>>(w2, w2f, 300, 600, NP2, Kp2);
        build_ec_kernel<<<(5 * 18 * DD + 255) / 256, 256, 0, stream>>>(e_emb1, e_emb2, ec);
        // CSR build
        hipMemsetAsync(deg, 0, (size_t)n * 4, stream);
        deg_kernel<<<(E + 255) / 256, 256, 0, stream>>>(ei, deg, E);
        scan1_kernel<<<nb, 256, 0, stream>>>(deg, cursor /*reuse as pre*/, blockSum, n);
        scan2_kernel<<<1, 256, 0, stream>>>(blockSum, nb);
        scan3_kernel<<<(n + 256) / 256, 256, 0, stream>>>(cursor, blockSum, rowPtr, deg /*reuse as cursor*/, n, E);
        fill_kernel<<<(E + 255) / 256, 256, 0, stream>>>(ei, ea, deg, edges, E);
        // agg zeroed once: k-pads + tail rows stay 0 across all layers
        hipMemsetAsync(agg, 0, (size_t)MpA * Kp1 * 2, stream);
        embed_kernel<<<(total4 + 255) / 256, 256, 0, stream>>>(x, x_emb1, x_emb2, h, total4);
    }

    const int gatherTotal = n * C4;
    const int nCol1 = NP1 / 128;   // 5
    const int nCol2 = NP2 / 128;   // 3
    const int g1 = nRowTP * nCol1; // 3920 blocks
    const int g2 = nRowTP * nCol2; // 2352 blocks

    for (int l = 0; l < 5; l++) {
        hipMemsetAsync(sum, 0, 2 * 320 * sizeof(float), stream);  // sum+sumsq contiguous
        gather_kernel<<<(gatherTotal + 255) / 256, 256, 0, stream>>>(
            h, rowPtr, edges, ec + (size_t)l * 18 * DD, scale, shift, l > 0 ? 1 : 0,
            agg, n);
        // GEMM1: agg[Mp,320] x w1[640,320] -> hid fp16 (relu, stride 640)
        mfma_gemm_lds<true, false><<<g1, 256, 0, stream>>>(
            agg, w1f + (size_t)l * NP1 * Kp1,
            b1 + (size_t)l * 600, hid, nullptr, nullptr, nullptr,
            n, Kp1, Kp2, 600, nCol1);
        // GEMM2: hid[Mp,640] x w2[384,640] -> h fp32 (stride 300) + fused BN stats
        mfma_gemm_lds<false, true><<<g2, 256, 0, stream>>>(
            hid, w2f + (size_t)l * NP2 * Kp2,
            b2 + (size_t)l * 300, nullptr, h, sum, sumsq,
            n, Kp2, 300, 300, nCol2);
        finalize_kernel<<<1, 320, 0, stream>>>(sum, sumsq, gamma + (size_t)l * DD,
                                               beta + (size_t)l * DD, scale, shift,
                                               1.0f / (float)n);
    }
    apply_kernel<<<(total4 + 255) / 256, 256, 0, stream>>>(h, scale, shift, h, total4);
}